// Round 5
// baseline (797.258 us; speedup 1.0000x reference)
//
#include <hip/hip_runtime.h>

typedef _Float16 f16;
typedef _Float16 f16x2 __attribute__((ext_vector_type(2)));
typedef _Float16 f16x4 __attribute__((ext_vector_type(4)));
typedef _Float16 f16x8 __attribute__((ext_vector_type(8)));
typedef float f32x4 __attribute__((ext_vector_type(4)));

#define N_NODES 50000
#define N_EDGES 600000

// ---------- async global->LDS, 16B per lane ----------
__device__ __forceinline__ void gl_lds16(const void* g, void* l) {
  __builtin_amdgcn_global_load_lds(
      (__attribute__((address_space(1))) void*)(g),
      (__attribute__((address_space(3))) void*)(l), 16, 0, 0);
}

// ---------- merged setup: deg atomics, W transposes, bias pads ----------
// (x->f16 conversion is fused into gemm1's LDS staging now)
// grid layout (blocks of 256):
//   [0, 2344)      deg atomics over 600000 edges
//   [2344, 4904)   W1^T  (655360 elems, exact)
//   [4904, 5504)   W2^T  (300 rows x 2 blocks)
//   [5504, 6104)   W3^T padded to 320 (300 rows x 2 blocks)
//   [6104, 6106)   bp2
//   [6106, 6108)   bp3
__global__ void k_setup(const float* __restrict__ W1, f16* __restrict__ w1h,
                        const float* __restrict__ W2, f16* __restrict__ w2h,
                        const float* __restrict__ W3, f16* __restrict__ w3h,
                        const float* __restrict__ b2, float* __restrict__ bp2,
                        const float* __restrict__ b3, float* __restrict__ bp3,
                        const int* __restrict__ edst, int* __restrict__ deg) {
  const int b = blockIdx.x, t = threadIdx.x;
  if (b < 2344) {
    int e = b * 256 + t;
    if (e < N_EDGES) atomicAdd(&deg[edst[e]], 1);
  } else if (b < 4904) {
    int idx = (b - 2344) * 256 + t;        // = n*1280 + k
    int n = idx / 1280, k = idx - n * 1280;
    w1h[idx] = (f16)W1[(size_t)k * 512 + n];
  } else if (b < 5504) {
    int bb = b - 4904;
    int n = bb >> 1, k = (bb & 1) * 256 + t;
    if (k < 512) w2h[(size_t)n * 512 + k] = (f16)W2[(size_t)k * 300 + n];
  } else if (b < 6104) {
    int bb = b - 5504;
    int n = bb >> 1, k = (bb & 1) * 256 + t;
    if (k < 320) w3h[(size_t)n * 320 + k] = (k < 300) ? (f16)W3[(size_t)k * 300 + n] : (f16)0.f;
  } else if (b < 6106) {
    int i = (b - 6104) * 256 + t;
    if (i < 320) bp2[i] = (i < 300) ? b2[i] : 0.f;
  } else {
    int i = (b - 6106) * 256 + t;
    if (i < 320) bp3[i] = (i < 300) ? b3[i] : 0.f;
  }
}

// ---------- multi-block exclusive scan of deg -> rowptr ----------
__device__ __forceinline__ int block_incl_scan256(int v, int t) {
  __shared__ int wsum[4];
  const int lane = t & 63, w = t >> 6;
  int incl = v;
#pragma unroll
  for (int off = 1; off < 64; off <<= 1) {
    int u = __shfl_up(incl, off, 64);
    if (lane >= off) incl += u;
  }
  if (lane == 63) wsum[w] = incl;
  __syncthreads();
  int add = 0;
#pragma unroll
  for (int k = 0; k < 4; ++k)
    if (k < w) add += wsum[k];
  return incl + add;
}

// per-block sums + dinv
__global__ void k_scan1(const int* __restrict__ deg, float* __restrict__ dinv,
                        int* __restrict__ bsum, int n) {
  __shared__ int ws4[4];
  const int t = threadIdx.x, b = blockIdx.x;
  const int i = b * 256 + t;
  int v = (i < n) ? deg[i] : 0;
  if (i < n) dinv[i] = rsqrtf((float)(v + 1));
  int s = v;
#pragma unroll
  for (int off = 1; off < 64; off <<= 1) s += __shfl_xor(s, off, 64);
  if ((t & 63) == 0) ws4[t >> 6] = s;
  __syncthreads();
  if (t == 0) bsum[b] = ws4[0] + ws4[1] + ws4[2] + ws4[3];
}

// scan the 196 block sums (single tiny block) + total -> rowptr[n]
__global__ void k_scan2(const int* __restrict__ bsum, int* __restrict__ bpre,
                        int* __restrict__ rowptr, int nb, int n) {
  const int t = threadIdx.x;
  int v = (t < nb) ? bsum[t] : 0;
  int incl = block_incl_scan256(v, t);
  if (t < nb) bpre[t] = incl - v;
  if (t == 255) rowptr[n] = incl;
}

// full exclusive positions; write rowptr and a second copy used as atomic cursor
__global__ void k_scan3(const int* __restrict__ deg, const int* __restrict__ bpre,
                        int* __restrict__ rowptr, int* __restrict__ rptr2, int n) {
  const int t = threadIdx.x, b = blockIdx.x;
  const int i = b * 256 + t;
  int v = (i < n) ? deg[i] : 0;
  int incl = block_incl_scan256(v, t);
  int ex = bpre[b] + incl - v;
  if (i < n) { rowptr[i] = ex; rptr2[i] = ex; }
}

// fill CSR: meta[pos] = {src, bitcast(norm)}; rptr2 doubles as cursor
__global__ void k_fill(const int* __restrict__ src, const int* __restrict__ dst,
                       int* __restrict__ rptr2, int2* __restrict__ meta,
                       const float* __restrict__ dinv, int E) {
  int e = blockIdx.x * 256 + threadIdx.x;
  if (e < E) {
    int d = dst[e], s = src[e];
    int pos = atomicAdd(&rptr2[d], 1);
    float w = dinv[s] * dinv[d];
    meta[pos] = make_int2(s, __float_as_int(w));
  }
}

// ---------- GEMM (f16 A): C[M,N] = A[M,K] * B^T[N,K] ----------
// 128x128 tile, BK=64, 4 waves, full-128B-line staging + XOR swizzle (R4).
__global__ __launch_bounds__(256, 3)
void gemm_f16_tn(const f16* __restrict__ A, const f16* __restrict__ B,
                 f16* __restrict__ C, int M, int N, int K,
                 int lda, int ldb, int ldc) {
  __shared__ __align__(16) f16 As[128 * 64];   // 16 KiB
  __shared__ __align__(16) f16 Bs[128 * 64];   // 16 KiB
  const int tid = threadIdx.x;
  const int wave = tid >> 6;
  const int lane = tid & 63;
  const int bm = blockIdx.y, bn = blockIdx.x;

  const int r8 = lane >> 3;                 // 0..7
  const int sunit = (lane & 7) ^ r8;        // XOR pre-swizzle of global src
  const char* aSrc[4];
  const char* bSrc[4];
#pragma unroll
  for (int c = 0; c < 4; ++c) {
    long ar = (long)bm * 128 + wave * 32 + c * 8 + r8; if (ar > M - 1) ar = M - 1;
    long br = (long)bn * 128 + wave * 32 + c * 8 + r8; if (br > N - 1) br = N - 1;
    aSrc[c] = (const char*)(A + ar * lda) + sunit * 16;
    bSrc[c] = (const char*)(B + br * ldb) + sunit * 16;
  }

  const int r16 = lane & 15;
  const int kq = lane >> 4;  // 0..3
  const int wm = wave & 1, wn = wave >> 1;

  int aoff[4][2], boff[4][2];
#pragma unroll
  for (int t = 0; t < 4; ++t) {
#pragma unroll
    for (int ks = 0; ks < 2; ++ks) {
      int arow = wm * 64 + t * 16 + r16;
      aoff[t][ks] = arow * 128 + ((((ks << 2) + kq) ^ (arow & 7)) << 4);
      int brow = wn * 64 + t * 16 + r16;
      boff[t][ks] = brow * 128 + ((((ks << 2) + kq) ^ (brow & 7)) << 4);
    }
  }

  f32x4 acc[4][4] = {};

  for (int k0 = 0; k0 < K; k0 += 64) {
    __syncthreads();
    const size_t kb = (size_t)k0 * 2;
#pragma unroll
    for (int c = 0; c < 4; ++c) {
      gl_lds16(aSrc[c] + kb, (char*)As + (wave * 32 + c * 8) * 128);
      gl_lds16(bSrc[c] + kb, (char*)Bs + (wave * 32 + c * 8) * 128);
    }
    __syncthreads();

#pragma unroll
    for (int ks = 0; ks < 2; ++ks) {
      f16x8 af[4], bf[4];
#pragma unroll
      for (int t = 0; t < 4; ++t) {
        af[t] = *(const f16x8*)((const char*)As + aoff[t][ks]);
        bf[t] = *(const f16x8*)((const char*)Bs + boff[t][ks]);
      }
#pragma unroll
      for (int mt = 0; mt < 4; ++mt)
#pragma unroll
        for (int nt = 0; nt < 4; ++nt)
          acc[mt][nt] = __builtin_amdgcn_mfma_f32_16x16x32_f16(af[mt], bf[nt], acc[mt][nt], 0, 0, 0);
    }
  }

  const int crow0 = bm * 128 + wm * 64;
  const int ccol0 = bn * 128 + wn * 64;
#pragma unroll
  for (int mt = 0; mt < 4; ++mt)
#pragma unroll
    for (int nt = 0; nt < 4; ++nt)
#pragma unroll
      for (int r = 0; r < 4; ++r) {
        int row = crow0 + mt * 16 + kq * 4 + r;
        int col = ccol0 + nt * 16 + r16;
        if (row < M && col < ldc)
          C[(size_t)row * ldc + col] = (col < N) ? (f16)acc[mt][nt][r] : (f16)0.f;
      }
}

// ---------- GEMM (fp32 A staged raw to LDS, cvt at frag read) ----------
// Same structure/barriers as gemm_f16_tn; A LDS is fp32 [128][64] = 32 KB,
// staged via gl_lds16 with a 32B-unit XOR swizzle (u32 ^= row&7) applied to
// the GLOBAL source (permutation within the wave's full-line footprint, so
// fetch efficiency is preserved; rule #21 both-sides pairing with the read).
// Fragment read: 2x ds_read_b128 (8 f32) + cvt to f16x8.
__global__ __launch_bounds__(256, 3)
void gemm_f32a_tn(const float* __restrict__ A, const f16* __restrict__ B,
                  f16* __restrict__ C, int M, int N, int K,
                  int lda, int ldb, int ldc) {
  __shared__ __align__(16) float As[128 * 64];   // 32 KiB fp32
  __shared__ __align__(16) f16 Bs[128 * 64];     // 16 KiB
  const int tid = threadIdx.x;
  const int wave = tid >> 6;
  const int lane = tid & 63;
  const int bm = blockIdx.y, bn = blockIdx.x;

  // ---- B staging (identical to gemm_f16_tn) ----
  const int r8 = lane >> 3;
  const int bunit = (lane & 7) ^ r8;
  const char* bSrc[4];
#pragma unroll
  for (int c = 0; c < 4; ++c) {
    long br = (long)bn * 128 + wave * 32 + c * 8 + r8; if (br > N - 1) br = N - 1;
    bSrc[c] = (const char*)(B + br * ldb) + bunit * 16;
  }

  // ---- A staging: 8 calls/wave; call c covers rows wave*32 + c*4 + (lane>>4),
  // 16 x 16B units per 256B row; global src 32B-unit pre-swizzled ----
  const int arow4 = lane >> 4;            // 0..3 row within call
  const int u16 = lane & 15;              // 16B unit in row
  const int u32h = u16 & 1;               // 16B half within 32B chunk
  const char* aSrc[8];
#pragma unroll
  for (int c = 0; c < 8; ++c) {
    int row_lo = c * 4 + arow4;           // 0..31 within wave's rows
    long ar = (long)bm * 128 + wave * 32 + row_lo; if (ar > M - 1) ar = M - 1;
    int s3 = row_lo & 7;
    int srcoff = (((u16 >> 1) ^ s3) << 5) + (u32h << 4);
    aSrc[c] = (const char*)(A + ar * lda) + srcoff;
  }

  const int r16 = lane & 15;
  const int kq = lane >> 4;
  const int wm = wave & 1, wn = wave >> 1;

  int aoff[4][2], boff[4][2];
#pragma unroll
  for (int t = 0; t < 4; ++t) {
#pragma unroll
    for (int ks = 0; ks < 2; ++ks) {
      int arow = wm * 64 + t * 16 + r16;
      // fp32 row = 256B; 32B chunk index (ks*4+kq) XOR (row&7)
      aoff[t][ks] = arow * 256 + ((((ks << 2) + kq) ^ (arow & 7)) << 5);
      int brow = wn * 64 + t * 16 + r16;
      boff[t][ks] = brow * 128 + ((((ks << 2) + kq) ^ (brow & 7)) << 4);
    }
  }

  f32x4 acc[4][4] = {};

  for (int k0 = 0; k0 < K; k0 += 64) {
    __syncthreads();
    const size_t kbA = (size_t)k0 * 4;   // fp32 bytes
    const size_t kbB = (size_t)k0 * 2;
#pragma unroll
    for (int c = 0; c < 4; ++c)
      gl_lds16(bSrc[c] + kbB, (char*)Bs + (wave * 32 + c * 8) * 128);
#pragma unroll
    for (int c = 0; c < 8; ++c)
      gl_lds16(aSrc[c] + kbA, (char*)As + (wave * 32 + c * 4) * 256);
    __syncthreads();

#pragma unroll
    for (int ks = 0; ks < 2; ++ks) {
      f16x8 af[4], bf[4];
#pragma unroll
      for (int t = 0; t < 4; ++t) {
        const char* ap = (const char*)As + aoff[t][ks];
        f32x4 lo = *(const f32x4*)(ap);
        f32x4 hi = *(const f32x4*)(ap + 16);
        f16x8 a;
        a[0] = (f16)lo[0]; a[1] = (f16)lo[1]; a[2] = (f16)lo[2]; a[3] = (f16)lo[3];
        a[4] = (f16)hi[0]; a[5] = (f16)hi[1]; a[6] = (f16)hi[2]; a[7] = (f16)hi[3];
        af[t] = a;
        bf[t] = *(const f16x8*)((const char*)Bs + boff[t][ks]);
      }
#pragma unroll
      for (int mt = 0; mt < 4; ++mt)
#pragma unroll
        for (int nt = 0; nt < 4; ++nt)
          acc[mt][nt] = __builtin_amdgcn_mfma_f32_16x16x32_f16(af[mt], bf[nt], acc[mt][nt], 0, 0, 0);
    }
  }

  const int crow0 = bm * 128 + wm * 64;
  const int ccol0 = bn * 128 + wn * 64;
#pragma unroll
  for (int mt = 0; mt < 4; ++mt)
#pragma unroll
    for (int nt = 0; nt < 4; ++nt)
#pragma unroll
      for (int r = 0; r < 4; ++r) {
        int row = crow0 + mt * 16 + kq * 4 + r;
        int col = ccol0 + nt * 16 + r16;
        if (row < M && col < ldc)
          C[(size_t)row * ldc + col] = (col < N) ? (f16)acc[mt][nt][r] : (f16)0.f;
      }
}

// ---------- aggregation v3: wave-per-node, coalesced meta prefetch + shuffle bcast ----------
// out[n] = relu( dinv[n]^2*h[n] + sum_e w[e]*h[src[e]] + b )
template <int LDH, int ACT, bool F16OUT, int DOUT>
__global__ __launch_bounds__(256, 8)
void agg_relu3(const f16* __restrict__ h, const int* __restrict__ rowptr,
               const int2* __restrict__ meta, const float* __restrict__ dinv,
               const float* __restrict__ bias, void* __restrict__ outp, int nNodes) {
  const int tid = threadIdx.x;
  const int lane = tid & 63;
  const int node = blockIdx.x * 4 + (tid >> 6);
  if (node >= nNodes) return;
  const int r0 = __builtin_amdgcn_readfirstlane(rowptr[node]);
  const int r1 = __builtin_amdgcn_readfirstlane(rowptr[node + 1]);
  const float dv = __builtin_bit_cast(
      float, __builtin_amdgcn_readfirstlane(__builtin_bit_cast(int, dinv[node])));

  const int hoff = (lane < ACT ? lane : ACT - 1) * 8;
  const f16* hp = h + hoff;

  float acc[8];
  {
    f16x8 v = *(const f16x8*)(hp + (size_t)node * LDH);
    const float w0 = dv * dv;
#pragma unroll
    for (int j = 0; j < 8; ++j) acc[j] = w0 * (float)v[j];
  }

  for (int base = r0; base < r1; base += 64) {
    const int idx = base + lane;
    int2 m = (idx < r1) ? meta[idx] : make_int2(0, 0);
    const int cnt = min(64, r1 - base);
    int j = 0;
    for (; j + 2 <= cnt; j += 2) {
      int s0 = __shfl(m.x, j, 64);
      int s1 = __shfl(m.x, j + 1, 64);
      float w0 = __int_as_float(__shfl(m.y, j, 64));
      float w1 = __int_as_float(__shfl(m.y, j + 1, 64));
      f16x8 v0 = *(const f16x8*)(hp + (size_t)s0 * LDH);
      f16x8 v1 = *(const f16x8*)(hp + (size_t)s1 * LDH);
#pragma unroll
      for (int q = 0; q < 8; ++q) acc[q] = fmaf(w0, (float)v0[q], acc[q]);
#pragma unroll
      for (int q = 0; q < 8; ++q) acc[q] = fmaf(w1, (float)v1[q], acc[q]);
    }
    if (j < cnt) {
      int s0 = __shfl(m.x, j, 64);
      float w0 = __int_as_float(__shfl(m.y, j, 64));
      f16x8 v0 = *(const f16x8*)(hp + (size_t)s0 * LDH);
#pragma unroll
      for (int q = 0; q < 8; ++q) acc[q] = fmaf(w0, (float)v0[q], acc[q]);
    }
  }

  float4 bv0 = *(const float4*)(bias + hoff);
  float4 bv1 = *(const float4*)(bias + hoff + 4);
  float o[8];
  o[0] = fmaxf(acc[0] + bv0.x, 0.f); o[1] = fmaxf(acc[1] + bv0.y, 0.f);
  o[2] = fmaxf(acc[2] + bv0.z, 0.f); o[3] = fmaxf(acc[3] + bv0.w, 0.f);
  o[4] = fmaxf(acc[4] + bv1.x, 0.f); o[5] = fmaxf(acc[5] + bv1.y, 0.f);
  o[6] = fmaxf(acc[6] + bv1.z, 0.f); o[7] = fmaxf(acc[7] + bv1.w, 0.f);

  if constexpr (F16OUT) {
    if (lane < ACT) {
      f16x8 ov;
#pragma unroll
      for (int j = 0; j < 8; ++j) ov[j] = (f16)o[j];
      *(f16x8*)((f16*)outp + (size_t)node * LDH + lane * 8) = ov;
    }
  } else {
    float* orow = (float*)outp + (size_t)node * DOUT + lane * 8;
    if (lane * 8 + 4 <= DOUT)
      *(float4*)(orow) = make_float4(o[0], o[1], o[2], o[3]);
    if (lane * 8 + 8 <= DOUT)
      *(float4*)(orow + 4) = make_float4(o[4], o[5], o[6], o[7]);
  }
}

extern "C" void kernel_launch(void* const* d_in, const int* in_sizes, int n_in,
                              void* d_out, int out_size, void* d_ws, size_t ws_size,
                              hipStream_t stream) {
  const float* x  = (const float*)d_in[0];
  const float* W1 = (const float*)d_in[1];
  const float* b1 = (const float*)d_in[2];
  const float* W2 = (const float*)d_in[3];
  const float* b2 = (const float*)d_in[4];
  const float* W3 = (const float*)d_in[5];
  const float* b3 = (const float*)d_in[6];
  const int* eidx = (const int*)d_in[7];
  const int* esrc = eidx;
  const int* edst = eidx + N_EDGES;
  float* out = (float*)d_out;

  char* ws = (char*)d_ws;
  f16* h2 = (f16*)(ws);                      // 50000*320*2  =  32,000,000
  f16* g2 = (f16*)(ws + 32000000);           // 32,000,000
  f16* h3 = (f16*)(ws + 64000000);           // 32,000,000
  f16* h1 = (f16*)(ws + 128000000);          // 50000*512*2  =  51,200,000
  f16* g1 = (f16*)(ws + 179200000);          // 51,200,000
  f16* w1h = (f16*)(ws + 230400000);         // 1,310,720
  f16* w2h = (f16*)(ws + 231710720);         //   307,200
  f16* w3h = (f16*)(ws + 232017920);         //   192,000
  float* bp2 = (float*)(ws + 232209920);     //     1,280
  float* bp3 = (float*)(ws + 232211200);     //     1,280
  int* deg    = (int*)(ws + 232212480);      //   200,000
  float* dinv = (float*)(ws + 232412480);    //   200,000
  int* rowptr = (int*)(ws + 232612480);      //   200,004
  int* rptr2  = (int*)(ws + 232812484);      //   200,004
  int* bsum   = (int*)(ws + 233012488);      //       800
  int* bpre   = (int*)(ws + 233013288);      //       800
  int2* meta  = (int2*)(ws + 233014088);     // 4,800,000 -> total 237,814,088

  hipMemsetAsync(deg, 0, N_NODES * sizeof(int), stream);

  // merged setup: deg atomics + W^T + bias pads (x convert fused into gemm1)
  k_setup<<<6108, 256, 0, stream>>>(W1, w1h, W2, w2h, W3, w3h,
                                    b2, bp2, b3, bp3, edst, deg);

  // multi-block scan + dinv
  k_scan1<<<196, 256, 0, stream>>>(deg, dinv, bsum, N_NODES);
  k_scan2<<<1, 256, 0, stream>>>(bsum, bpre, rowptr, 196, N_NODES);
  k_scan3<<<196, 256, 0, stream>>>(deg, bpre, rowptr, rptr2, N_NODES);
  k_fill<<<2344, 256, 0, stream>>>(esrc, edst, rptr2, meta, dinv, N_EDGES);

  // layer 1: h1 = cvt16(x) @ W1 ; g1 = relu(agg(h1) + b1)  (fp32-A LDS GEMM)
  gemm_f32a_tn<<<dim3(4, 391), 256, 0, stream>>>(x, w1h, h1, N_NODES, 512, 1280, 1280, 1280, 512);
  agg_relu3<512, 64, true, 0><<<12500, 256, 0, stream>>>(h1, rowptr, meta, dinv, b1, g1, N_NODES);

  // layer 2: h2 = g1 @ W2 (ldc=320, pad zeroed) ; g2 = relu(agg(h2) + bp2)
  gemm_f16_tn<<<dim3(3, 391), 256, 0, stream>>>(g1, w2h, h2, N_NODES, 300, 512, 512, 512, 320);
  agg_relu3<320, 40, true, 0><<<12500, 256, 0, stream>>>(h2, rowptr, meta, dinv, bp2, g2, N_NODES);

  // layer 3: h3 = g2 @ W3 (K=320 padded) ; out = relu(agg(h3) + bp3) fp32
  gemm_f16_tn<<<dim3(3, 391), 256, 0, stream>>>(g2, w3h, h3, N_NODES, 300, 320, 320, 320, 320);
  agg_relu3<320, 38, false, 300><<<12500, 256, 0, stream>>>(h3, rowptr, meta, dinv, bp3, out, N_NODES);
}